// Round 9
// baseline (561.562 us; speedup 1.0000x reference)
//
#include <hip/hip_runtime.h>
#include <hip/hip_bf16.h>
#include <stdint.h>

typedef __attribute__((ext_vector_type(4))) float  f32x4;
typedef __attribute__((ext_vector_type(8))) short  s16x8;
typedef __attribute__((ext_vector_type(4))) short  s16x4;

constexpr int I_SZ = 2048;
constexpr int O_SZ = 2048;
constexpr int T_SZ = 2048;
constexpr int B_MAX = 16;

// pre-tiled layout: per (bz, tile128, ktile32): 8KB block = 8 subtiles x 1KB;
// within a subtile, byte offset l*16 holds the MFMA fragment of lane l:
// row = l&15, k = 4*(l>>4) + {0..3} and 16 + 4*(l>>4) + {0..3}
constexpr size_t XT_ELEMS = (size_t)B_MAX * T_SZ * I_SZ;
constexpr size_t WT_ELEMS = (size_t)B_MAX * I_SZ * O_SZ;
constexpr size_t WS_NEEDED = (XT_ELEMS + WT_ELEMS) * sizeof(short); // 256 MB

__device__ __forceinline__ short f2bf(float f) {
    __hip_bfloat16 h = __float2bfloat16(f);
    return *reinterpret_cast<short*>(&h);
}

__device__ __forceinline__ void gload_lds16(const void* g, void* l) {
    __builtin_amdgcn_global_load_lds(
        (const __attribute__((address_space(1))) unsigned int*)g,
        (__attribute__((address_space(3))) unsigned int*)l, 16, 0, 0);
}

// ---------------- conversion: x fp32 [B][T][I] -> pre-tiled bf16 ----------------
__global__ __launch_bounds__(256) void convA(const float* __restrict__ x,
                                             short* __restrict__ xt) {
    const int c = blockIdx.x * 256 + threadIdx.x;
    const int l  = c & 63;
    const int mi = (c >> 6) & 7;
    const int kt = (c >> 9) & 63;
    const int rest = c >> 15;
    const int mt = rest & 15, bz = rest >> 4;
    const int lr = l & 15, hi = l >> 4;
    const int m = mt * 128 + mi * 16 + lr;
    const float* src = x + ((size_t)(bz * T_SZ + m)) * I_SZ + kt * 32 + 4 * hi;
    f32x4 a = *reinterpret_cast<const f32x4*>(src);
    f32x4 b = *reinterpret_cast<const f32x4*>(src + 16);
    s16x8 h = { f2bf(a[0]), f2bf(a[1]), f2bf(a[2]), f2bf(a[3]),
                f2bf(b[0]), f2bf(b[1]), f2bf(b[2]), f2bf(b[3]) };
    *reinterpret_cast<s16x8*>(xt + (size_t)c * 8) = h;
}

// ------- conversion: W fp32 [dom][I][O] gathered+transposed -> pre-tiled bf16 ----
__global__ __launch_bounds__(256) void convB(const float* __restrict__ fcw,
                                             const int* __restrict__ dom_id,
                                             short* __restrict__ wt) {
    const int c = blockIdx.x * 256 + threadIdx.x;
    const int l  = c & 63;
    const int ni = (c >> 6) & 7;
    const int kt = (c >> 9) & 63;
    const int rest = c >> 15;
    const int nt = rest & 15, bz = rest >> 4;
    const int lr = l & 15, hi = l >> 4;
    const int n = nt * 128 + ni * 16 + lr;
    const int dom = dom_id[bz];
    const float* src = fcw + (size_t)dom * ((size_t)I_SZ * O_SZ)
                           + (size_t)(kt * 32 + 4 * hi) * O_SZ + n;
    short h[8];
    #pragma unroll
    for (int j = 0; j < 4; ++j) {
        h[j]     = f2bf(src[(size_t)j * O_SZ]);
        h[4 + j] = f2bf(src[(size_t)(16 + j) * O_SZ]);
    }
    *reinterpret_cast<s16x8*>(wt + (size_t)c * 8) =
        *reinterpret_cast<s16x8*>(h);
}

// ======== V0/V1: 256x256 tile, 8 waves, ring-4, R6 3-barrier schedule ========
// DRAIN=0: counted vmcnt(8). DRAIN=1: vmcnt(0) full drain. Grid 256 blocks/slice.
template<int DRAIN>
__global__ __launch_bounds__(512, 2) void gemm256(
        const short* __restrict__ xt, const short* __restrict__ wt,
        const float* __restrict__ bw, const int* __restrict__ dom_id,
        float* __restrict__ out, int bz0) {
    __shared__ short As[4][8192];
    __shared__ short Bs[4][8192];

    const int bid = blockIdx.x;                 // 256 blocks: 8 XCD x 32
    const int swz = (bid & 7) * 32 + (bid >> 3);
    const int bz = bz0 + (swz >> 6);
    const int mb = (swz >> 3) & 7;
    const int nb = swz & 7;

    const short* Abase = xt + (size_t)(bz * 16 + mb * 2) * 64 * 4096;
    const short* Bbase = wt + (size_t)(bz * 16 + nb * 2) * 64 * 4096;

    const int t = threadIdx.x;
    const int wv = t >> 6, l = t & 63;
    const int wm = wv >> 2, wn = wv & 3;
    const int lr = l & 15, hi = l >> 4;
    const int bni = wn >> 1, bsub = (wn & 1) * 4;

    auto stageA = [&](int buf, int kt) {
        #pragma unroll
        for (int i = 0; i < 2; ++i) {
            const int c = wv * 2 + i;
            const int mi = c >> 3, inner = c & 7;
            gload_lds16(Abase + (size_t)(mi * 64 + kt) * 4096 + inner * 512 + l * 8,
                        &As[buf][c * 512]);
        }
    };
    auto stageB = [&](int buf, int kt) {
        #pragma unroll
        for (int i = 0; i < 2; ++i) {
            const int c = wv * 2 + i;
            const int ni = c >> 3, inner = c & 7;
            gload_lds16(Bbase + (size_t)(ni * 64 + kt) * 4096 + inner * 512 + l * 8,
                        &Bs[buf][c * 512]);
        }
    };

    f32x4 acc[8][4] = {};

    stageA(0, 0); stageB(0, 0);
    stageA(1, 1); stageB(1, 1);
    stageA(2, 2); stageB(2, 2);

    for (int kt = 0; kt < 64; ++kt) {
        const int cur = kt & 3;
        const int pre = (kt + 3) & 3;
        const int pkt = (kt + 3 > 63) ? 63 : kt + 3;

        if constexpr (DRAIN) {
            asm volatile("s_waitcnt vmcnt(0)" ::: "memory");
        } else {
            asm volatile("s_waitcnt vmcnt(8)" ::: "memory");
        }
        asm volatile("s_barrier" ::: "memory");

        s16x8 af[4], bq[4];
        #pragma unroll
        for (int g = 0; g < 4; ++g)
            bq[g] = *reinterpret_cast<const s16x8*>(
                        &Bs[cur][bni * 4096 + (bsub + g) * 512 + l * 8]);
        #pragma unroll
        for (int f = 0; f < 4; ++f)
            af[f] = *reinterpret_cast<const s16x8*>(
                        &As[cur][wm * 4096 + f * 512 + l * 8]);
        stageA(pre, pkt);
        asm volatile("s_barrier" ::: "memory");

        __builtin_amdgcn_s_setprio(1);
        #pragma unroll
        for (int f = 0; f < 4; ++f)
            #pragma unroll
            for (int g = 0; g < 4; ++g)
                acc[f][g] = __builtin_amdgcn_mfma_f32_16x16x32_bf16(
                                af[f], bq[g], acc[f][g], 0, 0, 0);
        __builtin_amdgcn_s_setprio(0);

        s16x8 af2[4];
        #pragma unroll
        for (int f = 0; f < 4; ++f)
            af2[f] = *reinterpret_cast<const s16x8*>(
                        &As[cur][wm * 4096 + (4 + f) * 512 + l * 8]);
        stageB(pre, pkt);
        asm volatile("s_barrier" ::: "memory");

        __builtin_amdgcn_s_setprio(1);
        #pragma unroll
        for (int f = 0; f < 4; ++f)
            #pragma unroll
            for (int g = 0; g < 4; ++g)
                acc[4 + f][g] = __builtin_amdgcn_mfma_f32_16x16x32_bf16(
                                    af2[f], bq[g], acc[4 + f][g], 0, 0, 0);
        __builtin_amdgcn_s_setprio(0);
    }

    asm volatile("s_waitcnt vmcnt(0)" ::: "memory");

    const int dom = dom_id[bz];
    const int col0 = nb * 256 + wn * 64;
    float bias[4];
    #pragma unroll
    for (int g = 0; g < 4; ++g)
        bias[g] = bw[dom * O_SZ + col0 + g * 16 + lr];

    const size_t obase = ((size_t)bz * T_SZ + mb * 256 + wm * 128) * O_SZ + col0;
    #pragma unroll
    for (int f = 0; f < 8; ++f) {
        #pragma unroll
        for (int r = 0; r < 4; ++r) {
            const int row = f * 16 + hi * 4 + r;
            float* orow = out + obase + (size_t)row * O_SZ;
            #pragma unroll
            for (int g = 0; g < 4; ++g)
                orow[g * 16 + lr] = acc[f][g][r] + bias[g];
        }
    }
}

// ======== V2: 128x128 tile, 4 waves, ring-2, 32KB LDS -> ~4 blocks/CU ========
// Per iter: [vmcnt(0) (queue holds ONLY stage(kt), issued 1 iter ago); BAR;
// stage(kt+1) (after BAR -> WAR-safe); 8 ds_read; 16 MFMA]. Occupancy covers
// the stage-wait: independent blocks' phases interleave on the CU.
__global__ __launch_bounds__(256, 4) void gemm128_r2(
        const short* __restrict__ xt, const short* __restrict__ wt,
        const float* __restrict__ bw, const int* __restrict__ dom_id,
        float* __restrict__ out, int bz0) {
    __shared__ short As[2][4096];
    __shared__ short Bs[2][4096];

    const int bid = blockIdx.x;                  // 1024 blocks: 8 XCD x 128
    const int swz = (bid & 7) * 128 + (bid >> 3);
    const int bz = bz0 + (swz >> 8);
    const int mt = (swz >> 4) & 15;
    const int nt = swz & 15;

    const short* Abase = xt + (size_t)(bz * 16 + mt) * 64 * 4096;
    const short* Bbase = wt + (size_t)(bz * 16 + nt) * 64 * 4096;

    const int t = threadIdx.x;
    const int wv = t >> 6, l = t & 63;
    const int wr = wv >> 1, wc = wv & 1;        // 64x64 quadrant
    const int lr = l & 15, hi = l >> 4;

    auto stage = [&](int buf, int kt) {
        #pragma unroll
        for (int i = 0; i < 2; ++i) {
            const int c = wv * 2 + i;           // 0..7
            gload_lds16(Abase + (size_t)kt * 4096 + c * 512 + l * 8, &As[buf][c * 512]);
            gload_lds16(Bbase + (size_t)kt * 4096 + c * 512 + l * 8, &Bs[buf][c * 512]);
        }
    };

    f32x4 acc[4][4] = {};
    stage(0, 0);

    for (int kt = 0; kt < 64; ++kt) {
        const int d = kt & 1, nd = d ^ 1;
        asm volatile("s_waitcnt vmcnt(0)" ::: "memory");   // stage(kt) landed
        asm volatile("s_barrier" ::: "memory");            // global + WAR gate
        stage(nd, (kt + 1 > 63) ? 63 : kt + 1);

        s16x8 af[4], bq[4];
        #pragma unroll
        for (int im = 0; im < 4; ++im)
            af[im] = *reinterpret_cast<const s16x8*>(&As[d][(wr * 4 + im) * 512 + l * 8]);
        #pragma unroll
        for (int in = 0; in < 4; ++in)
            bq[in] = *reinterpret_cast<const s16x8*>(&Bs[d][(wc * 4 + in) * 512 + l * 8]);

        __builtin_amdgcn_s_setprio(1);
        #pragma unroll
        for (int im = 0; im < 4; ++im)
            #pragma unroll
            for (int in = 0; in < 4; ++in)
                acc[im][in] = __builtin_amdgcn_mfma_f32_16x16x32_bf16(
                                  af[im], bq[in], acc[im][in], 0, 0, 0);
        __builtin_amdgcn_s_setprio(0);
    }

    asm volatile("s_waitcnt vmcnt(0)" ::: "memory");

    const int dom = dom_id[bz];
    const int col0 = nt * 128 + wc * 64;
    float bias[4];
    #pragma unroll
    for (int in = 0; in < 4; ++in)
        bias[in] = bw[dom * O_SZ + col0 + in * 16 + lr];

    const size_t obase = ((size_t)bz * T_SZ + mt * 128 + wr * 64) * O_SZ + col0;
    #pragma unroll
    for (int im = 0; im < 4; ++im) {
        #pragma unroll
        for (int r = 0; r < 4; ++r) {
            const int row = im * 16 + hi * 4 + r;
            float* orow = out + obase + (size_t)row * O_SZ;
            #pragma unroll
            for (int in = 0; in < 4; ++in)
                orow[in * 16 + lr] = acc[im][in][r] + bias[in];
        }
    }
}

// ======== V3: 128x128 tile, 4 waves, ring-4, 64KB LDS, counted vmcnt(8) ========
// 2 blocks/CU. Per iter: [vmcnt(8) (12 outstanding -> retires stage(kt)); BAR;
// stage(kt+3); 8 ds_read; 16 MFMA].
__global__ __launch_bounds__(256, 4) void gemm128_r4(
        const short* __restrict__ xt, const short* __restrict__ wt,
        const float* __restrict__ bw, const int* __restrict__ dom_id,
        float* __restrict__ out, int bz0) {
    __shared__ short As[4][4096];
    __shared__ short Bs[4][4096];

    const int bid = blockIdx.x;
    const int swz = (bid & 7) * 128 + (bid >> 3);
    const int bz = bz0 + (swz >> 8);
    const int mt = (swz >> 4) & 15;
    const int nt = swz & 15;

    const short* Abase = xt + (size_t)(bz * 16 + mt) * 64 * 4096;
    const short* Bbase = wt + (size_t)(bz * 16 + nt) * 64 * 4096;

    const int t = threadIdx.x;
    const int wv = t >> 6, l = t & 63;
    const int wr = wv >> 1, wc = wv & 1;
    const int lr = l & 15, hi = l >> 4;

    auto stage = [&](int buf, int kt) {
        #pragma unroll
        for (int i = 0; i < 2; ++i) {
            const int c = wv * 2 + i;
            gload_lds16(Abase + (size_t)kt * 4096 + c * 512 + l * 8, &As[buf][c * 512]);
            gload_lds16(Bbase + (size_t)kt * 4096 + c * 512 + l * 8, &Bs[buf][c * 512]);
        }
    };

    f32x4 acc[4][4] = {};
    stage(0, 0); stage(1, 1); stage(2, 2);

    for (int kt = 0; kt < 64; ++kt) {
        const int d = kt & 3;
        asm volatile("s_waitcnt vmcnt(8)" ::: "memory");   // stage(kt) landed
        asm volatile("s_barrier" ::: "memory");
        stage((kt + 3) & 3, (kt + 3 > 63) ? 63 : kt + 3);

        s16x8 af[4], bq[4];
        #pragma unroll
        for (int im = 0; im < 4; ++im)
            af[im] = *reinterpret_cast<const s16x8*>(&As[d][(wr * 4 + im) * 512 + l * 8]);
        #pragma unroll
        for (int in = 0; in < 4; ++in)
            bq[in] = *reinterpret_cast<const s16x8*>(&Bs[d][(wc * 4 + in) * 512 + l * 8]);

        __builtin_amdgcn_s_setprio(1);
        #pragma unroll
        for (int im = 0; im < 4; ++im)
            #pragma unroll
            for (int in = 0; in < 4; ++in)
                acc[im][in] = __builtin_amdgcn_mfma_f32_16x16x32_bf16(
                                  af[im], bq[in], acc[im][in], 0, 0, 0);
        __builtin_amdgcn_s_setprio(0);
    }

    asm volatile("s_waitcnt vmcnt(0)" ::: "memory");

    const int dom = dom_id[bz];
    const int col0 = nt * 128 + wc * 64;
    float bias[4];
    #pragma unroll
    for (int in = 0; in < 4; ++in)
        bias[in] = bw[dom * O_SZ + col0 + in * 16 + lr];

    const size_t obase = ((size_t)bz * T_SZ + mt * 128 + wr * 64) * O_SZ + col0;
    #pragma unroll
    for (int im = 0; im < 4; ++im) {
        #pragma unroll
        for (int r = 0; r < 4; ++r) {
            const int row = im * 16 + hi * 4 + r;
            float* orow = out + obase + (size_t)row * O_SZ;
            #pragma unroll
            for (int in = 0; in < 4; ++in)
                orow[in * 16 + lr] = acc[im][in][r] + bias[in];
        }
    }
}

// =============== fallback (round-1 kernel) if workspace is too small ===============
constexpr int BM = 128, BN = 128, BK = 32;
constexpr int LDK = 40;
constexpr int NKT = I_SZ / BK;

__global__ __launch_bounds__(256) void dal_gemm(
    const float* __restrict__ x, const int* __restrict__ dom_id,
    const float* __restrict__ fcw, const float* __restrict__ bw,
    float* __restrict__ out)
{
    __shared__ short As[2][BM * LDK];
    __shared__ short Bs[2][BN * LDK];
    const int bz = blockIdx.z;
    const int m0 = blockIdx.y * BM, n0 = blockIdx.x * BN;
    const int dom = dom_id[bz];
    const float* Ag = x + ((size_t)bz * T_SZ + m0) * I_SZ;
    const float* Wg = fcw + (size_t)dom * ((size_t)I_SZ * O_SZ) + n0;
    const int t = threadIdx.x;
    const int am = t >> 3, ac = (t & 7) << 2;
    const int bk = (t >> 5) << 2, bn = (t & 31) << 2;
    const int wv = t >> 6, lane = t & 63;
    const int wr = (wv >> 1) << 6, wc = (wv & 1) << 6;
    const int hi = lane >> 4, lr = lane & 15;
    f32x4 acc[4][4] = {};
    f32x4 ra[4], rb[4];
    auto load_tile = [&](int kb) {
        #pragma unroll
        for (int p = 0; p < 4; ++p)
            ra[p] = *reinterpret_cast<const f32x4*>(Ag + (size_t)(am + 32 * p) * I_SZ + kb + ac);
        #pragma unroll
        for (int r = 0; r < 4; ++r)
            rb[r] = *reinterpret_cast<const f32x4*>(Wg + (size_t)(kb + bk + r) * O_SZ + bn);
    };
    auto store_tile = [&](int buf) {
        #pragma unroll
        for (int p = 0; p < 4; ++p) {
            s16x4 h = { f2bf(ra[p][0]), f2bf(ra[p][1]), f2bf(ra[p][2]), f2bf(ra[p][3]) };
            *reinterpret_cast<s16x4*>(&As[buf][(am + 32 * p) * LDK + ac]) = h;
        }
        #pragma unroll
        for (int i = 0; i < 4; ++i) {
            s16x4 h = { f2bf(rb[0][i]), f2bf(rb[1][i]), f2bf(rb[2][i]), f2bf(rb[3][i]) };
            *reinterpret_cast<s16x4*>(&Bs[buf][(bn + i) * LDK + bk]) = h;
        }
    };
    load_tile(0);
    store_tile(0);
    __syncthreads();
    for (int kt = 0; kt < NKT; ++kt) {
        const int cur = kt & 1;
        if (kt + 1 < NKT) load_tile((kt + 1) * BK);
        s16x8 af[4], bfr[4];
        #pragma unroll
        for (int im = 0; im < 4; ++im) {
            const short* p = &As[cur][(wr + im * 16 + lr) * LDK + 4 * hi];
            s16x4 lo = *reinterpret_cast<const s16x4*>(p);
            s16x4 hh = *reinterpret_cast<const s16x4*>(p + 16);
            af[im] = __builtin_shufflevector(lo, hh, 0, 1, 2, 3, 4, 5, 6, 7);
        }
        #pragma unroll
        for (int in = 0; in < 4; ++in) {
            const short* p = &Bs[cur][(wc + in * 16 + lr) * LDK + 4 * hi];
            s16x4 lo = *reinterpret_cast<const s16x4*>(p);
            s16x4 hh = *reinterpret_cast<const s16x4*>(p + 16);
            bfr[in] = __builtin_shufflevector(lo, hh, 0, 1, 2, 3, 4, 5, 6, 7);
        }
        #pragma unroll
        for (int im = 0; im < 4; ++im)
            #pragma unroll
            for (int in = 0; in < 4; ++in)
                acc[im][in] = __builtin_amdgcn_mfma_f32_16x16x32_bf16(
                                  af[im], bfr[in], acc[im][in], 0, 0, 0);
        if (kt + 1 < NKT) store_tile(cur ^ 1);
        __syncthreads();
    }
    float bias[4];
    #pragma unroll
    for (int in = 0; in < 4; ++in)
        bias[in] = bw[dom * O_SZ + n0 + wc + in * 16 + lr];
    const size_t obase = ((size_t)bz * T_SZ + m0) * O_SZ + n0;
    #pragma unroll
    for (int im = 0; im < 4; ++im) {
        #pragma unroll
        for (int r = 0; r < 4; ++r) {
            const int row = wr + im * 16 + hi * 4 + r;
            float* orow = out + obase + (size_t)row * O_SZ;
            #pragma unroll
            for (int in = 0; in < 4; ++in)
                orow[wc + in * 16 + lr] = acc[im][in][r] + bias[in];
        }
    }
}

extern "C" void kernel_launch(void* const* d_in, const int* in_sizes, int n_in,
                              void* d_out, int out_size, void* d_ws, size_t ws_size,
                              hipStream_t stream) {
    const float* x   = (const float*)d_in[0];
    const int*   dom = (const int*)d_in[1];
    const float* fcw = (const float*)d_in[2];
    const float* bw  = (const float*)d_in[3];
    float* out = (float*)d_out;
    const int B = in_sizes[1];   // 16

    if (ws_size >= WS_NEEDED && B == B_MAX) {
        short* xt = (short*)d_ws;
        short* wt = xt + XT_ELEMS;
        const int chunks = B * 16 * 64 * 512;             // 8,388,608
        convA<<<chunks / 256, 256, 0, stream>>>(x, xt);
        convB<<<chunks / 256, 256, 0, stream>>>(fcw, dom, wt);
        // ablation round: 4 variants, 4 bz-slices each, separate dispatches
        gemm256<0><<<dim3(256),  dim3(512), 0, stream>>>(xt, wt, bw, dom, out, 0);
        gemm256<1><<<dim3(256),  dim3(512), 0, stream>>>(xt, wt, bw, dom, out, 4);
        gemm128_r2<<<dim3(1024), dim3(256), 0, stream>>>(xt, wt, bw, dom, out, 8);
        gemm128_r4<<<dim3(1024), dim3(256), 0, stream>>>(xt, wt, bw, dom, out, 12);
    } else {
        dim3 grid(O_SZ / BN, T_SZ / BM, B);
        dal_gemm<<<grid, dim3(256), 0, stream>>>(x, dom, fcw, bw, out);
    }
}